// Round 14
// baseline (39789.963 us; speedup 1.0000x reference)
//
#include <hip/hip_runtime.h>
#include <cmath>

// MessageDecoder: 20-step LSTM greedy decoder, B=32768, H=512, 65 actions.
// Round 14: bitwise-r2 chains; the one untried shape fitting BOTH empirical
// constraints discovered over r7-r13:
//  - allocator never grants >~128 arch VGPRs (r12/r7: picked 128; r13: 64)
//    and allocates one occupancy tier above waves_per_eu max -> with (3,3)
//    it should target ~128. Demand must be <=128.
//  - ncols=1 shapes are LDS-broadcast-heavy (16 b128/k4/wave per 256 FMA);
//    ncols=2 halves that ratio. TM=8,ncols=2: demand ~120 <= 128. The only
//    ncols=2 shape under the ceiling.
//  - waves(3,3): 3 waves/EU TLP for load latency; LDS ratio 0.1875*3 < 1.
//  - whh32 single-base pack (8 imm-offset dwordx4/k4), direct wa4 logits.
//  - per-output-element fmaf chains identical to r2/r7 -> bitwise output.

#define HH      512
#define G4      2048
#define NACTS   65
#define NAP     80    // Wa padded cols
#define NVOCAB  67
#define MAXLEN  20
#define NB      32768
#define TM      8
#define NTH     256
#define EOS_TOK 0
#define PAD_TOK 65
#define BOS_TOK 66
#define HSTR    516

// gxa4[(a*HH + t)*4 + gate] = emb[a].W_ih[gate*HH+t] + b_ih[c] + b_hh[c]
__global__ void prep_gxa_kernel(const float* __restrict__ emb,
                                const float* __restrict__ W_ih,
                                const float* __restrict__ b_ih,
                                const float* __restrict__ b_hh,
                                float* __restrict__ gxa4) {
  int id = blockIdx.x * blockDim.x + threadIdx.x;
  if (id >= NVOCAB * G4) return;
  int a = id / G4, rem = id - a * G4;
  int t = rem >> 2, gate = rem & 3;
  int c = gate * HH + t;
  const float* e = emb + (size_t)a * HH;
  const float* w = W_ih + (size_t)c * HH;
  float acc = 0.f;
  for (int k = 0; k < HH; ++k) acc = fmaf(e[k], w[k], acc);
  gxa4[id] = acc + b_ih[c] + b_hh[c];
}

// k4-major float4 pack: dst[(k4*cols + c)*4 + j] = src[c*HH + k4*4 + j]
__global__ void prep_w4_kernel(const float* __restrict__ src,
                               float* __restrict__ dst, int cols) {
  int id = blockIdx.x * blockDim.x + threadIdx.x;
  if (id >= cols * HH) return;
  int k4 = id / (cols * 4);
  int rem = id - k4 * cols * 4;
  int c = rem >> 2, j = rem & 3;
  dst[id] = src[(size_t)c * HH + k4 * 4 + j];
}

// per-thread-contiguous W_hh pack for NTH=256, 2 cols/thread:
// dst[(k4*256 + t)*32 + (j*4+g)*4 + e] = W_hh[(g*512 + t + j*256)*512 + k4*4 + e]
__global__ void prep_whh32_kernel(const float* __restrict__ W_hh,
                                  float* __restrict__ dst) {
  int id = blockIdx.x * blockDim.x + threadIdx.x;
  if (id >= 128 * 256 * 32) return;
  int k4 = id >> 13;            // /8192
  int rem = id & 8191;
  int t = rem >> 5;
  int q = (rem >> 2) & 7;       // j*4 + g
  int e = id & 3;
  int g = q & 3, j = q >> 2;
  int c = t + j * 256;
  dst[id] = W_hh[((size_t)g * 512 + c) * 512 + k4 * 4 + e];
}

// Wa k4-major pack, zero-padded to NAP cols: dst[(k4*NAP + a)*4 + j]
__global__ void prep_wa4_kernel(const float* __restrict__ Wa,
                                float* __restrict__ dst) {
  int id = blockIdx.x * blockDim.x + threadIdx.x;
  if (id >= (HH / 4) * NAP * 4) return;
  int k4 = id / (NAP * 4);
  int rem = id - k4 * NAP * 4;
  int a = rem >> 2, j = rem & 3;
  dst[id] = (a < NACTS) ? Wa[(size_t)a * HH + k4 * 4 + j] : 0.f;
}

__global__ void ws_sentinel_kernel(float* out) {
  out[threadIdx.x] = 123000.f;
}

// acc = h.w*w.w -> h.z*w.z -> h.y*w.y -> h.x*w.x nested (r2's exact chain)
#define FMA4(acc, h, wv) \
  acc = fmaf((h).x, (wv).x, fmaf((h).y, (wv).y, fmaf((h).z, (wv).z, fmaf((h).w, (wv).w, (acc)))))

__global__
__attribute__((amdgpu_flat_work_group_size(NTH, NTH), amdgpu_waves_per_eu(3, 3)))
void decode_kernel(const float* __restrict__ encoded,
                   const float* __restrict__ gxa4,
                   const float* __restrict__ whh32, // [(k4*256 + t)*32 + (j*4+g)*4 + e]
                   const float* __restrict__ wc4,   // [(k4*512 + c)*4 + j]
                   const float* __restrict__ wh4,
                   const float* __restrict__ bc,
                   const float* __restrict__ bh,
                   const float* __restrict__ wa4,   // [(k4*80 + a)*4 + j]
                   const float* __restrict__ ba,
                   float* __restrict__ out) {
  __shared__ float sh_h[TM][HSTR];
  __shared__ float sh_logits[TM][NACTS + 3];
  __shared__ int   sh_last[TM];
  __shared__ int   sh_stop[TM];
  __shared__ float sh_ent[TM];
  __shared__ int   sh_len[TM];

  const int t = threadIdx.x;               // owns cols t and t+256
  const int row0 = blockIdx.x * TM;

  // ---- stage encoded[row0:+8][:] into sh_h (coalesced float4) ----
  #pragma unroll
  for (int i = 0; i < (TM * HH / 4) / NTH; ++i) {   // 4 float4s per thread
    int f4 = i * NTH + t;
    int idx = f4 * 4;
    int r = idx >> 9;
    int c = idx & (HH - 1);
    *reinterpret_cast<float4*>(&sh_h[r][c]) =
        *reinterpret_cast<const float4*>(encoded + (size_t)(row0 + r) * HH + c);
  }
  if (t < TM) { sh_last[t] = BOS_TOK; sh_stop[t] = 0; sh_ent[t] = 0.f; sh_len[t] = 0; }
  __syncthreads();

  // ---- h0 = enc@Wc^T + bc ; c0 = enc@Wh^T + bh (reference's intentional swap) ----
  float hacc[2][TM], cacc[2][TM];
  #pragma unroll
  for (int j = 0; j < 2; ++j)
    #pragma unroll
    for (int r = 0; r < TM; ++r) { hacc[j][r] = 0.f; cacc[j][r] = 0.f; }
  #pragma unroll 1
  for (int k4 = 0; k4 < HH / 4; ++k4) {
    const float* wcb = wc4 + ((size_t)k4 * HH + t) * 4;
    const float* whb = wh4 + ((size_t)k4 * HH + t) * 4;
    float4 wc0 = *reinterpret_cast<const float4*>(wcb);
    float4 wc1 = *reinterpret_cast<const float4*>(wcb + 1024);
    float4 wh0 = *reinterpret_cast<const float4*>(whb);
    float4 wh1 = *reinterpret_cast<const float4*>(whb + 1024);
    #pragma unroll
    for (int r = 0; r < TM; ++r) {
      float4 e = *reinterpret_cast<const float4*>(&sh_h[r][k4 * 4]);
      FMA4(hacc[0][r], e, wc0);
      FMA4(hacc[1][r], e, wc1);
      FMA4(cacc[0][r], e, wh0);
      FMA4(cacc[1][r], e, wh1);
    }
  }
  __syncthreads();   // done reading enc from sh_h
  float cst[2][TM];
  {
    float bc0 = bc[t], bc1 = bc[t + 256];
    float bh0 = bh[t], bh1 = bh[t + 256];
    #pragma unroll
    for (int r = 0; r < TM; ++r) {
      sh_h[r][t] = hacc[0][r] + bc0;
      sh_h[r][t + 256] = hacc[1][r] + bc1;
      cst[0][r] = cacc[0][r] + bh0;
      cst[1][r] = cacc[1][r] + bh1;
    }
  }
  __syncthreads();

  // ---- 20 decode steps ----
  for (int step = 0; step < MAXLEN; ++step) {
    // x-side gates: two float4 gathers per row (i,f,g,o interleaved)
    float ai[2][TM], af[2][TM], ag[2][TM], ao[2][TM];
    #pragma unroll
    for (int r = 0; r < TM; ++r) {
      const float* g0 = gxa4 + ((size_t)sh_last[r] * HH + t) * 4;
      float4 ga = *reinterpret_cast<const float4*>(g0);
      float4 gb = *reinterpret_cast<const float4*>(g0 + 1024);
      ai[0][r] = ga.x; af[0][r] = ga.y; ag[0][r] = ga.z; ao[0][r] = ga.w;
      ai[1][r] = gb.x; af[1][r] = gb.y; ag[1][r] = gb.z; ao[1][r] = gb.w;
    }
    // gates += h @ W_hh^T : 1 base ptr, 8 imm-offset dwordx4, 64 FMA4 per k4
    {
      const float4* wp = reinterpret_cast<const float4*>(whh32) + (size_t)t * 8;
      #pragma unroll 1
      for (int k4 = 0; k4 < HH / 4; ++k4, wp += 2048) {
        float4 wi0 = wp[0];
        float4 wf0 = wp[1];
        float4 wg0 = wp[2];
        float4 wo0 = wp[3];
        float4 wi1 = wp[4];
        float4 wf1 = wp[5];
        float4 wg1 = wp[6];
        float4 wo1 = wp[7];
        #pragma unroll
        for (int r = 0; r < TM; ++r) {
          float4 h4 = *reinterpret_cast<const float4*>(&sh_h[r][k4 * 4]);
          FMA4(ai[0][r], h4, wi0);
          FMA4(af[0][r], h4, wf0);
          FMA4(ag[0][r], h4, wg0);
          FMA4(ao[0][r], h4, wo0);
          FMA4(ai[1][r], h4, wi1);
          FMA4(af[1][r], h4, wf1);
          FMA4(ag[1][r], h4, wg1);
          FMA4(ao[1][r], h4, wo1);
        }
      }
    }
    __syncthreads();   // all lanes done reading old sh_h

    // pointwise LSTM cell; write new h  (identical arithmetic to r2)
    #pragma unroll
    for (int j = 0; j < 2; ++j) {
      int col = t + j * 256;
      #pragma unroll
      for (int r = 0; r < TM; ++r) {
        float iv = 1.f / (1.f + expf(-ai[j][r]));
        float fv = 1.f / (1.f + expf(-af[j][r]));
        float gv = tanhf(ag[j][r]);
        float ov = 1.f / (1.f + expf(-ao[j][r]));
        float cn = fmaf(fv, cst[j][r], iv * gv);
        cst[j][r] = cn;
        sh_h[r][col] = ov * tanhf(cn);
      }
    }
    __syncthreads();   // new h visible

    // logits = h @ Wa^T + ba ; direct coalesced reads of k4-major wa4
    // thread (r_lg = t>>5, a_lg = t&31): actions a_lg, a_lg+32, a_lg+64
    {
      const int r_lg = t >> 5;     // 0..7
      const int a_lg = t & 31;     // 0..31
      #pragma unroll 1
      for (int a = a_lg; a < NAP; a += 32) {
        float acc = 0.f;
        #pragma unroll 4
        for (int k4 = 0; k4 < HH / 4; ++k4) {
          float4 h4 = *reinterpret_cast<const float4*>(&sh_h[r_lg][k4 * 4]);
          float4 w4 = *reinterpret_cast<const float4*>(wa4 + ((size_t)k4 * NAP + a) * 4);
          FMA4(acc, h4, w4);
        }
        if (a < NACTS) sh_logits[r_lg][a] = acc + ba[a];
      }
    }
    __syncthreads();

    // per-row softmax / argmax / entropy / state update (r2 verbatim)
    if (t < TM) {
      const int r = t;
      float m = sh_logits[r][0];
      int am = 0;
      #pragma unroll 1
      for (int a = 1; a < NACTS; ++a) {
        float v = sh_logits[r][a];
        if (v > m) { m = v; am = a; }
      }
      float s = 0.f;
      #pragma unroll 1
      for (int a = 0; a < NACTS; ++a) s += expf(sh_logits[r][a] - m);
      float logZ = m + logf(s);
      float pl = 0.f;
      #pragma unroll 1
      for (int a = 0; a < NACTS; ++a) {
        float l = sh_logits[r][a];
        pl = fmaf(expf(l - logZ), l, pl);
      }
      float ent = logZ - pl;
      int stopped = sh_stop[r];
      float lp   = stopped ? 0.f : (sh_logits[r][am] - logZ);
      float entc = stopped ? 0.f : ent;
      int act = stopped ? PAD_TOK : am;
      int grow = row0 + r;
      out[NB + (size_t)grow * MAXLEN + step] = lp;                        // log_probs
      out[NB + (size_t)NB * MAXLEN + (size_t)grow * MAXLEN + step] = (float)act;  // message
      sh_ent[r] += entc;
      if (act != PAD_TOK) sh_len[r] += 1;
      if (act == EOS_TOK) sh_stop[r] = 1;
      sh_last[r] = act;
    }
    __syncthreads();
  }

  if (t < TM) {
    int r = t, grow = row0 + r;
    float lenf = (float)sh_len[r];
    out[grow] = sh_ent[r] / lenf;                           // entropy
    out[NB + 2 * (size_t)NB * MAXLEN + grow] = lenf;        // message_len
  }
}

extern "C" void kernel_launch(void* const* d_in, const int* in_sizes, int n_in,
                              void* d_out, int out_size, void* d_ws, size_t ws_size,
                              hipStream_t stream) {
  const float* encoded = (const float*)d_in[0];
  const float* emb     = (const float*)d_in[1];
  const float* W_ih    = (const float*)d_in[2];
  const float* W_hh    = (const float*)d_in[3];
  const float* b_ih    = (const float*)d_in[4];
  const float* b_hh    = (const float*)d_in[5];
  const float* Wc      = (const float*)d_in[6];
  const float* bc      = (const float*)d_in[7];
  const float* Wh      = (const float*)d_in[8];
  const float* bh      = (const float*)d_in[9];
  const float* Wa      = (const float*)d_in[10];
  const float* ba      = (const float*)d_in[11];
  float* out = (float*)d_out;

  size_t need = ((size_t)NVOCAB * G4 + (size_t)G4 * HH + 2 * (size_t)HH * HH
                 + (size_t)(HH / 4) * NAP * 4) * 4;
  if (ws_size < need) {
    ws_sentinel_kernel<<<1, 64, 0, stream>>>(out);
    return;
  }

  float* ws    = (float*)d_ws;
  float* gxa4  = ws;                          // 67*2048
  float* whh32 = gxa4 + NVOCAB * G4;          // 2048*512 (per-thread pack)
  float* wc4   = whh32 + (size_t)G4 * HH;     // 512*512
  float* wh4   = wc4 + (size_t)HH * HH;       // 512*512
  float* wa4   = wh4 + (size_t)HH * HH;       // 128*80*4

  prep_gxa_kernel<<<(NVOCAB * G4 + 255) / 256, 256, 0, stream>>>(emb, W_ih, b_ih, b_hh, gxa4);
  prep_whh32_kernel<<<(128 * 256 * 32 + 255) / 256, 256, 0, stream>>>(W_hh, whh32);
  prep_w4_kernel<<<(HH * HH + 255) / 256, 256, 0, stream>>>(Wc, wc4, HH);
  prep_w4_kernel<<<(HH * HH + 255) / 256, 256, 0, stream>>>(Wh, wh4, HH);
  prep_wa4_kernel<<<((HH / 4) * NAP * 4 + 255) / 256, 256, 0, stream>>>(Wa, wa4);

  decode_kernel<<<NB / TM, NTH, 0, stream>>>(encoded, gxa4, whh32, wc4, wh4,
                                             bc, bh, wa4, ba, out);
}

// Round 15
// 20734.351 us; speedup vs baseline: 1.9190x; 1.9190x over previous
//
#include <hip/hip_runtime.h>
#include <cmath>

// MessageDecoder: 20-step LSTM greedy decoder, B=32768, H=512, 65 actions.
// Round 15: r7 champion (21.0ms) + the LDS-diet that doubles its TLP.
//  - r7: 2 cols/thread, NTH=256, launch_bounds(256,2) -> allocator picks 128
//    regs (the max it will ever grant, per r7-r14 sweep). r7 was capped at
//    2 blocks/CU by 70.6KB LDS (sh_wa staging = 33KB of it).
//  - this round = r8's kernel (direct k4-major wa4 logits, LDS 37.9KB,
//    bitwise-verified) with r8's one mistake fixed: launch_bounds(256,2)
//    not (256,1). 37.9KB x 4 = 151KB <= 160 -> 4 blocks/CU = 4 waves/SIMD.
//  - per-output-element fmaf chains identical to r2/r7/r8 -> bitwise output

#define HH      512
#define G4      2048
#define NACTS   65
#define NAP     80    // Wa padded cols
#define NVOCAB  67
#define MAXLEN  20
#define NB      32768
#define TM      16
#define NTH     256
#define EOS_TOK 0
#define PAD_TOK 65
#define BOS_TOK 66
#define HSTR    516

// gxa4[(a*HH + t)*4 + gate] = emb[a].W_ih[gate*HH+t] + b_ih[c] + b_hh[c]
__global__ void prep_gxa_kernel(const float* __restrict__ emb,
                                const float* __restrict__ W_ih,
                                const float* __restrict__ b_ih,
                                const float* __restrict__ b_hh,
                                float* __restrict__ gxa4) {
  int id = blockIdx.x * blockDim.x + threadIdx.x;
  if (id >= NVOCAB * G4) return;
  int a = id / G4, rem = id - a * G4;
  int t = rem >> 2, gate = rem & 3;
  int c = gate * HH + t;
  const float* e = emb + (size_t)a * HH;
  const float* w = W_ih + (size_t)c * HH;
  float acc = 0.f;
  for (int k = 0; k < HH; ++k) acc = fmaf(e[k], w[k], acc);
  gxa4[id] = acc + b_ih[c] + b_hh[c];
}

// k4-major float4 pack: dst[(k4*cols + c)*4 + j] = src[c*HH + k4*4 + j]
__global__ void prep_w4_kernel(const float* __restrict__ src,
                               float* __restrict__ dst, int cols) {
  int id = blockIdx.x * blockDim.x + threadIdx.x;
  if (id >= cols * HH) return;
  int k4 = id / (cols * 4);
  int rem = id - k4 * cols * 4;
  int c = rem >> 2, j = rem & 3;
  dst[id] = src[(size_t)c * HH + k4 * 4 + j];
}

// Wa k4-major pack, zero-padded to NAP cols: dst[(k4*NAP + a)*4 + j]
__global__ void prep_wa4_kernel(const float* __restrict__ Wa,
                                float* __restrict__ dst) {
  int id = blockIdx.x * blockDim.x + threadIdx.x;
  if (id >= (HH / 4) * NAP * 4) return;
  int k4 = id / (NAP * 4);
  int rem = id - k4 * NAP * 4;
  int a = rem >> 2, j = rem & 3;
  dst[id] = (a < NACTS) ? Wa[(size_t)a * HH + k4 * 4 + j] : 0.f;
}

__global__ void ws_sentinel_kernel(float* out) {
  out[threadIdx.x] = 123000.f;
}

// acc = h.w*w.w -> h.z*w.z -> h.y*w.y -> h.x*w.x nested (r2's exact chain)
#define FMA4(acc, h, wv) \
  acc = fmaf((h).x, (wv).x, fmaf((h).y, (wv).y, fmaf((h).z, (wv).z, fmaf((h).w, (wv).w, (acc)))))

__global__ __launch_bounds__(NTH, 2)
void decode_kernel(const float* __restrict__ encoded,
                   const float* __restrict__ gxa4,
                   const float* __restrict__ whh4,  // [(k4*2048 + gate*512 + c)*4 + j]
                   const float* __restrict__ wc4,   // [(k4*512 + c)*4 + j]
                   const float* __restrict__ wh4,
                   const float* __restrict__ bc,
                   const float* __restrict__ bh,
                   const float* __restrict__ wa4,   // [(k4*80 + a)*4 + j]
                   const float* __restrict__ ba,
                   float* __restrict__ out) {
  __shared__ float sh_h[TM][HSTR];
  __shared__ float sh_logits[TM][NACTS + 3];
  __shared__ int   sh_last[TM];
  __shared__ int   sh_stop[TM];
  __shared__ float sh_ent[TM];
  __shared__ int   sh_len[TM];

  const int t = threadIdx.x;               // owns cols t and t+256
  const int row0 = blockIdx.x * TM;

  // ---- stage encoded[row0:+16][:] into sh_h (coalesced float4) ----
  #pragma unroll
  for (int i = 0; i < (TM * HH / 4) / NTH; ++i) {   // 8 float4s per thread
    int f4 = i * NTH + t;
    int idx = f4 * 4;
    int r = idx >> 9;
    int c = idx & (HH - 1);
    *reinterpret_cast<float4*>(&sh_h[r][c]) =
        *reinterpret_cast<const float4*>(encoded + (size_t)(row0 + r) * HH + c);
  }
  if (t < TM) { sh_last[t] = BOS_TOK; sh_stop[t] = 0; sh_ent[t] = 0.f; sh_len[t] = 0; }
  __syncthreads();

  // ---- h0 = enc@Wc^T + bc ; c0 = enc@Wh^T + bh (reference's intentional swap) ----
  float hacc[2][TM], cacc[2][TM];
  #pragma unroll
  for (int j = 0; j < 2; ++j)
    #pragma unroll
    for (int r = 0; r < TM; ++r) { hacc[j][r] = 0.f; cacc[j][r] = 0.f; }
  #pragma unroll 1
  for (int k4 = 0; k4 < HH / 4; ++k4) {
    const float* wcb = wc4 + ((size_t)k4 * HH + t) * 4;
    const float* whb = wh4 + ((size_t)k4 * HH + t) * 4;
    float4 wc0 = *reinterpret_cast<const float4*>(wcb);
    float4 wc1 = *reinterpret_cast<const float4*>(wcb + 1024);
    float4 wh0 = *reinterpret_cast<const float4*>(whb);
    float4 wh1 = *reinterpret_cast<const float4*>(whb + 1024);
    #pragma unroll
    for (int r = 0; r < TM; ++r) {
      float4 e = *reinterpret_cast<const float4*>(&sh_h[r][k4 * 4]);
      FMA4(hacc[0][r], e, wc0);
      FMA4(hacc[1][r], e, wc1);
      FMA4(cacc[0][r], e, wh0);
      FMA4(cacc[1][r], e, wh1);
    }
  }
  __syncthreads();   // done reading enc from sh_h
  float cst[2][TM];
  {
    float bc0 = bc[t], bc1 = bc[t + 256];
    float bh0 = bh[t], bh1 = bh[t + 256];
    #pragma unroll
    for (int r = 0; r < TM; ++r) {
      sh_h[r][t] = hacc[0][r] + bc0;
      sh_h[r][t + 256] = hacc[1][r] + bc1;
      cst[0][r] = cacc[0][r] + bh0;
      cst[1][r] = cacc[1][r] + bh1;
    }
  }
  __syncthreads();

  // ---- 20 decode steps ----
  for (int step = 0; step < MAXLEN; ++step) {
    // x-side gates: two float4 gathers per row (i,f,g,o interleaved)
    float ai[2][TM], af[2][TM], ag[2][TM], ao[2][TM];
    #pragma unroll
    for (int r = 0; r < TM; ++r) {
      const float* g0 = gxa4 + ((size_t)sh_last[r] * HH + t) * 4;
      float4 ga = *reinterpret_cast<const float4*>(g0);
      float4 gb = *reinterpret_cast<const float4*>(g0 + 1024);
      ai[0][r] = ga.x; af[0][r] = ga.y; ag[0][r] = ga.z; ao[0][r] = ga.w;
      ai[1][r] = gb.x; af[1][r] = gb.y; ag[1][r] = gb.z; ao[1][r] = gb.w;
    }
    // gates += h @ W_hh^T  (512 FMA per k4 per thread, 16 LDS broadcasts)
    #pragma unroll 1
    for (int k4 = 0; k4 < HH / 4; ++k4) {
      const float* wb = whh4 + (size_t)k4 * (G4 * 4) + t * 4;
      float4 wi0 = *reinterpret_cast<const float4*>(wb);
      float4 wf0 = *reinterpret_cast<const float4*>(wb + 2048);
      float4 wg0 = *reinterpret_cast<const float4*>(wb + 4096);
      float4 wo0 = *reinterpret_cast<const float4*>(wb + 6144);
      float4 wi1 = *reinterpret_cast<const float4*>(wb + 1024);
      float4 wf1 = *reinterpret_cast<const float4*>(wb + 2048 + 1024);
      float4 wg1 = *reinterpret_cast<const float4*>(wb + 4096 + 1024);
      float4 wo1 = *reinterpret_cast<const float4*>(wb + 6144 + 1024);
      #pragma unroll
      for (int r = 0; r < TM; ++r) {
        float4 h4 = *reinterpret_cast<const float4*>(&sh_h[r][k4 * 4]);
        FMA4(ai[0][r], h4, wi0);
        FMA4(af[0][r], h4, wf0);
        FMA4(ag[0][r], h4, wg0);
        FMA4(ao[0][r], h4, wo0);
        FMA4(ai[1][r], h4, wi1);
        FMA4(af[1][r], h4, wf1);
        FMA4(ag[1][r], h4, wg1);
        FMA4(ao[1][r], h4, wo1);
      }
    }
    __syncthreads();   // all lanes done reading old sh_h

    // pointwise LSTM cell; write new h  (identical arithmetic to r2)
    #pragma unroll
    for (int j = 0; j < 2; ++j) {
      int col = t + j * 256;
      #pragma unroll
      for (int r = 0; r < TM; ++r) {
        float iv = 1.f / (1.f + expf(-ai[j][r]));
        float fv = 1.f / (1.f + expf(-af[j][r]));
        float gv = tanhf(ag[j][r]);
        float ov = 1.f / (1.f + expf(-ao[j][r]));
        float cn = fmaf(fv, cst[j][r], iv * gv);
        cst[j][r] = cn;
        sh_h[r][col] = ov * tanhf(cn);
      }
    }
    __syncthreads();   // new h visible

    // logits = h @ Wa^T + ba ; direct coalesced reads of k4-major wa4
    // thread (r_lg, a_lg) computes actions a_lg, a_lg+16, ..., a_lg+64
    {
      const int r_lg = t >> 4;     // 0..15
      const int a_lg = t & 15;     // 0..15
      #pragma unroll 1
      for (int ab = 0; ab < 5; ++ab) {
        int a = ab * 16 + a_lg;    // 0..79 (>=65 are zero-padded cols)
        float acc = 0.f;
        #pragma unroll 4
        for (int k4 = 0; k4 < HH / 4; ++k4) {
          float4 h4 = *reinterpret_cast<const float4*>(&sh_h[r_lg][k4 * 4]);
          float4 w4 = *reinterpret_cast<const float4*>(wa4 + ((size_t)k4 * NAP + a) * 4);
          FMA4(acc, h4, w4);
        }
        if (a < NACTS) sh_logits[r_lg][a] = acc + ba[a];
      }
    }
    __syncthreads();

    // per-row softmax / argmax / entropy / state update (r2 verbatim)
    if (t < TM) {
      const int r = t;
      float m = sh_logits[r][0];
      int am = 0;
      #pragma unroll 1
      for (int a = 1; a < NACTS; ++a) {
        float v = sh_logits[r][a];
        if (v > m) { m = v; am = a; }
      }
      float s = 0.f;
      #pragma unroll 1
      for (int a = 0; a < NACTS; ++a) s += expf(sh_logits[r][a] - m);
      float logZ = m + logf(s);
      float pl = 0.f;
      #pragma unroll 1
      for (int a = 0; a < NACTS; ++a) {
        float l = sh_logits[r][a];
        pl = fmaf(expf(l - logZ), l, pl);
      }
      float ent = logZ - pl;
      int stopped = sh_stop[r];
      float lp   = stopped ? 0.f : (sh_logits[r][am] - logZ);
      float entc = stopped ? 0.f : ent;
      int act = stopped ? PAD_TOK : am;
      int grow = row0 + r;
      out[NB + (size_t)grow * MAXLEN + step] = lp;                        // log_probs
      out[NB + (size_t)NB * MAXLEN + (size_t)grow * MAXLEN + step] = (float)act;  // message
      sh_ent[r] += entc;
      if (act != PAD_TOK) sh_len[r] += 1;
      if (act == EOS_TOK) sh_stop[r] = 1;
      sh_last[r] = act;
    }
    __syncthreads();
  }

  if (t < TM) {
    int r = t, grow = row0 + r;
    float lenf = (float)sh_len[r];
    out[grow] = sh_ent[r] / lenf;                           // entropy
    out[NB + 2 * (size_t)NB * MAXLEN + grow] = lenf;        // message_len
  }
}

extern "C" void kernel_launch(void* const* d_in, const int* in_sizes, int n_in,
                              void* d_out, int out_size, void* d_ws, size_t ws_size,
                              hipStream_t stream) {
  const float* encoded = (const float*)d_in[0];
  const float* emb     = (const float*)d_in[1];
  const float* W_ih    = (const float*)d_in[2];
  const float* W_hh    = (const float*)d_in[3];
  const float* b_ih    = (const float*)d_in[4];
  const float* b_hh    = (const float*)d_in[5];
  const float* Wc      = (const float*)d_in[6];
  const float* bc      = (const float*)d_in[7];
  const float* Wh      = (const float*)d_in[8];
  const float* bh      = (const float*)d_in[9];
  const float* Wa      = (const float*)d_in[10];
  const float* ba      = (const float*)d_in[11];
  float* out = (float*)d_out;

  size_t need = ((size_t)NVOCAB * G4 + (size_t)G4 * HH + 2 * (size_t)HH * HH
                 + (size_t)(HH / 4) * NAP * 4) * 4;
  if (ws_size < need) {
    ws_sentinel_kernel<<<1, 64, 0, stream>>>(out);
    return;
  }

  float* ws   = (float*)d_ws;
  float* gxa4 = ws;                         // 67*2048
  float* whh4 = gxa4 + NVOCAB * G4;         // 2048*512 (k4-major packed)
  float* wc4  = whh4 + (size_t)HH * G4;     // 512*512
  float* wh4  = wc4 + (size_t)HH * HH;      // 512*512
  float* wa4  = wh4 + (size_t)HH * HH;      // 128*80*4

  prep_gxa_kernel<<<(NVOCAB * G4 + 255) / 256, 256, 0, stream>>>(emb, W_ih, b_ih, b_hh, gxa4);
  prep_w4_kernel<<<(G4 * HH + 255) / 256, 256, 0, stream>>>(W_hh, whh4, G4);
  prep_w4_kernel<<<(HH * HH + 255) / 256, 256, 0, stream>>>(Wc, wc4, HH);
  prep_w4_kernel<<<(HH * HH + 255) / 256, 256, 0, stream>>>(Wh, wh4, HH);
  prep_wa4_kernel<<<((HH / 4) * NAP * 4 + 255) / 256, 256, 0, stream>>>(Wa, wa4);

  decode_kernel<<<NB / TM, NTH, 0, stream>>>(encoded, gxa4, whh4, wc4, wh4,
                                             bc, bh, wa4, ba, out);
}